// Round 12
// baseline (450.685 us; speedup 1.0000x reference)
//
#include <hip/hip_runtime.h>

#define D 256
#define N_NODES 100000
#define N_HE 25000
#define N_CONN 400000
#define N_PAD 100032    // N_NODES padded to 64-row multiple for DMA
#define N_HE_PAD 25024  // N_HE padded to 64-row multiple for DMA

constexpr float MEAN_EPS = 1e-8f;
constexpr float LN_EPS   = 1e-5f;
constexpr float SLOPE    = 0.2f;

typedef __attribute__((ext_vector_type(8))) short short8;
typedef __attribute__((ext_vector_type(4))) float f32x4;
typedef __attribute__((ext_vector_type(16))) float f32x16;
typedef __attribute__((ext_vector_type(4))) unsigned short ushort4v;

static __device__ __forceinline__ unsigned short f2bf(float f) {
  unsigned int u = __builtin_bit_cast(unsigned int, f);
  u = (u + 0x7FFFu + ((u >> 16) & 1u)) >> 16;
  return (unsigned short)u;
}
static __device__ __forceinline__ float bf2f(unsigned short u) {
  return __builtin_bit_cast(float, (unsigned int)u << 16);
}

// ---------------------------------------------------------------------------
// x (fp32) -> bf16
// ---------------------------------------------------------------------------
__global__ __launch_bounds__(256) void conv_x(
    const float* __restrict__ in, unsigned short* __restrict__ out, int n8) {
  int i = blockIdx.x * 256 + threadIdx.x;
  int stride = gridDim.x * 256;
  for (; i < n8; i += stride) {
    float4 a = ((const float4*)in)[(size_t)i * 2];
    float4 b = ((const float4*)in)[(size_t)i * 2 + 1];
    short8 o;
    o[0] = (short)f2bf(a.x); o[1] = (short)f2bf(a.y);
    o[2] = (short)f2bf(a.z); o[3] = (short)f2bf(a.w);
    o[4] = (short)f2bf(b.x); o[5] = (short)f2bf(b.y);
    o[6] = (short)f2bf(b.z); o[7] = (short)f2bf(b.w);
    ((short8*)out)[i] = o;
  }
}

// ---------------------------------------------------------------------------
// Adjacency build (indices are constant inputs; rebuilt every call)
// ---------------------------------------------------------------------------
__global__ __launch_bounds__(256) void hist_kernel(
    const int* __restrict__ node_idx, const int* __restrict__ he_idx,
    int* __restrict__ he_deg, int* __restrict__ n_deg) {
  int c = blockIdx.x * 256 + threadIdx.x;
  if (c < N_CONN) {
    atomicAdd(&he_deg[he_idx[c]], 1);
    atomicAdd(&n_deg[node_idx[c]], 1);
  }
}

__global__ __launch_bounds__(256) void alloc_kernel(
    const int* __restrict__ he_deg, const int* __restrict__ n_deg,
    int* __restrict__ totals,
    int* __restrict__ he_start, int* __restrict__ he_cur,
    int* __restrict__ n_start, int* __restrict__ n_cur) {
  int i = blockIdx.x * 256 + threadIdx.x;
  if (i < N_HE) {
    int s = atomicAdd(&totals[0], he_deg[i]);
    he_start[i] = s;
    he_cur[i] = s;
  }
  if (i < N_NODES) {
    int s = atomicAdd(&totals[1], n_deg[i]);
    n_start[i] = s;
    n_cur[i] = s;
  }
}

__global__ __launch_bounds__(256) void fill_kernel(
    const int* __restrict__ node_idx, const int* __restrict__ he_idx,
    int* __restrict__ he_cur, int* __restrict__ n_cur,
    int* __restrict__ he_list, int* __restrict__ n_list) {
  int c = blockIdx.x * 256 + threadIdx.x;
  if (c < N_CONN) {
    int n = node_idx[c];
    int e = he_idx[c];
    int p = atomicAdd(&he_cur[e], 1);
    he_list[p] = n;
    int q = atomicAdd(&n_cur[n], 1);
    n_list[q] = e;
  }
}

// ---------------------------------------------------------------------------
// Weight convert+transpose: Wt[n][k] = bf16(W[k][n]).
// ---------------------------------------------------------------------------
__global__ __launch_bounds__(256) void convert_w(
    const float* __restrict__ Wnode, const float* __restrict__ Whe,
    unsigned short* __restrict__ Wt) {
  int m = blockIdx.x >> 4;
  int tile = blockIdx.x & 15;
  int k0 = (tile >> 2) * 64, n0 = (tile & 3) * 64;
  const float* Win = (m < 2) ? (Wnode + (size_t)m * 65536)
                             : (Whe + (size_t)(m - 2) * 65536);
  unsigned short* Wout = Wt + (size_t)m * 65536;
  __shared__ unsigned short T[64][65];
  int t = threadIdx.x;
  int r = t >> 6, c = t & 63;
  #pragma unroll 4
  for (int i = 0; i < 16; ++i) {
    int kr = i * 4 + r;
    T[kr][c] = f2bf(Win[(size_t)(k0 + kr) * 256 + n0 + c]);
  }
  __syncthreads();
  #pragma unroll 4
  for (int i = 0; i < 16; ++i) {
    int nr = i * 4 + r;
    Wout[(size_t)(n0 + nr) * 256 + k0 + c] = T[c][nr];
  }
}

// ---------------------------------------------------------------------------
// GEMM: bf16 A staged via global_load_lds width=16 (A/B-validated winner).
// Double-buffered (2x32KB), grid-stride; one __syncthreads per tile.
// Optional per-row scale hwp (hyperedge weight); A padded to 64-row multiple.
// ---------------------------------------------------------------------------
__global__ __launch_bounds__(512, 4) void gemm_pipe(
    const unsigned short* __restrict__ A, const unsigned short* __restrict__ Wt,
    const float* __restrict__ bias, const float* __restrict__ hwp,
    unsigned short* __restrict__ out, int M, int ntiles) {
  __shared__ unsigned short As[2][64 * 256];  // 2 x 32 KB
  const int t = threadIdx.x;
  const int wave = t >> 6, lane = t & 63;
  const int l31 = lane & 31, lhi = lane >> 5;
  const int colbase = wave * 32;

  // ---- preload + pin B ----
  f32x4 B[16];
  {
    const unsigned short* bp = Wt + (size_t)(colbase + l31) * 256 + lhi * 8;
    #pragma unroll
    for (int kc = 0; kc < 16; ++kc)
      B[kc] = *(const f32x4*)(bp + kc * 16);
  }
  #pragma unroll
  for (int kc = 0; kc < 16; ++kc)
    asm volatile("" : "+v"(B[kc]));
  float biasv = bias[colbase + l31];

  // Per-lane swizzled source offsets (ushort units within a 64x256 tile).
  int goff[4];
  #pragma unroll
  for (int i = 0; i < 4; ++i) {
    int c = i * 512 + t;
    int row = c >> 5, s = c & 31;
    int ss = (s & 24) | ((s & 7) ^ (row & 7));
    goff[i] = row * 256 + ss * 8;
  }

  // ---- prologue: stage first tile into buf 0 ----
  {
    const unsigned short* base = A + (size_t)blockIdx.x * 64 * 256;
    #pragma unroll
    for (int i = 0; i < 4; ++i) {
      __builtin_amdgcn_global_load_lds(
          (const __attribute__((address_space(1))) void*)(base + goff[i]),
          (__attribute__((address_space(3))) void*)((char*)As[0] + i * 8192 + wave * 1024),
          16, 0, 0);
    }
  }

  int cur = 0;
  for (int tile = blockIdx.x; tile < ntiles; tile += gridDim.x) {
    __syncthreads();  // drains vmcnt -> As[cur] DMA complete; prev compute done

    const int next = tile + gridDim.x;
    if (next < ntiles) {
      const unsigned short* base = A + (size_t)next * 64 * 256;
      #pragma unroll
      for (int i = 0; i < 4; ++i) {
        __builtin_amdgcn_global_load_lds(
            (const __attribute__((address_space(1))) void*)(base + goff[i]),
            (__attribute__((address_space(3))) void*)((char*)As[cur ^ 1] + i * 8192 + wave * 1024),
            16, 0, 0);
      }
    }

    // ---- compute current tile ----
    const int row0 = tile * 64;
    const char* Ab = (const char*)As[cur];
    f32x16 acc0 = (f32x16)0.f, acc1 = (f32x16)0.f;
    #pragma unroll
    for (int kc = 0; kc < 16; ++kc) {
      unsigned int ad0 = (unsigned)(l31 * 512 + kc * 32 + lhi * 16) ^ (unsigned)((l31 & 7) << 4);
      short8 a0 = *(const short8*)(Ab + ad0);
      unsigned int ad1 = (unsigned)((32 + l31) * 512 + kc * 32 + lhi * 16) ^ (unsigned)((l31 & 7) << 4);
      short8 a1 = *(const short8*)(Ab + ad1);
      short8 b = __builtin_bit_cast(short8, B[kc]);
      acc0 = __builtin_amdgcn_mfma_f32_32x32x16_bf16(a0, b, acc0, 0, 0, 0);
      acc1 = __builtin_amdgcn_mfma_f32_32x32x16_bf16(a1, b, acc1, 0, 0, 0);
    }

    const int col = colbase + l31;
    #pragma unroll
    for (int rt = 0; rt < 2; ++rt) {
      #pragma unroll
      for (int reg = 0; reg < 16; ++reg) {
        int row = (reg & 3) + 8 * (reg >> 2) + 4 * lhi;
        int grow = row0 + rt * 32 + row;
        if (grow < M) {
          float v = ((rt == 0) ? acc0[reg] : acc1[reg]) + biasv;
          if (hwp) v *= hwp[grow];
          out[(size_t)grow * D + col] = f2bf(v);
        }
      }
    }
    cur ^= 1;
  }
}

// ---------------------------------------------------------------------------
// Gather nodes -> hyperedge mean (bf16 in/out). One wave per hyperedge,
// 4/block, grid 6250 (~24 waves/CU for latency hiding). Unrolled x8.
// ---------------------------------------------------------------------------
__global__ __launch_bounds__(256) void gather_he(
    const unsigned short* __restrict__ xt, const int* __restrict__ he_start,
    const int* __restrict__ he_deg, const int* __restrict__ he_list,
    unsigned short* __restrict__ he_mean) {
  int e = blockIdx.x * 4 + (threadIdx.x >> 6);
  if (e >= N_HE) return;
  int lane = threadIdx.x & 63;
  int s = he_start[e];
  int deg = he_deg[e];

  float a0 = 0.f, a1 = 0.f, a2 = 0.f, a3 = 0.f;
  int i = 0;
  for (; i + 8 <= deg; i += 8) {
    int n0 = he_list[s + i + 0];
    int n1 = he_list[s + i + 1];
    int n2 = he_list[s + i + 2];
    int n3 = he_list[s + i + 3];
    int n4 = he_list[s + i + 4];
    int n5 = he_list[s + i + 5];
    int n6 = he_list[s + i + 6];
    int n7 = he_list[s + i + 7];
    ushort4v v0 = ((const ushort4v*)(xt + (size_t)n0 * D))[lane];
    ushort4v v1 = ((const ushort4v*)(xt + (size_t)n1 * D))[lane];
    ushort4v v2 = ((const ushort4v*)(xt + (size_t)n2 * D))[lane];
    ushort4v v3 = ((const ushort4v*)(xt + (size_t)n3 * D))[lane];
    ushort4v v4 = ((const ushort4v*)(xt + (size_t)n4 * D))[lane];
    ushort4v v5 = ((const ushort4v*)(xt + (size_t)n5 * D))[lane];
    ushort4v v6 = ((const ushort4v*)(xt + (size_t)n6 * D))[lane];
    ushort4v v7 = ((const ushort4v*)(xt + (size_t)n7 * D))[lane];
    a0 += bf2f(v0[0]) + bf2f(v1[0]) + bf2f(v2[0]) + bf2f(v3[0])
        + bf2f(v4[0]) + bf2f(v5[0]) + bf2f(v6[0]) + bf2f(v7[0]);
    a1 += bf2f(v0[1]) + bf2f(v1[1]) + bf2f(v2[1]) + bf2f(v3[1])
        + bf2f(v4[1]) + bf2f(v5[1]) + bf2f(v6[1]) + bf2f(v7[1]);
    a2 += bf2f(v0[2]) + bf2f(v1[2]) + bf2f(v2[2]) + bf2f(v3[2])
        + bf2f(v4[2]) + bf2f(v5[2]) + bf2f(v6[2]) + bf2f(v7[2]);
    a3 += bf2f(v0[3]) + bf2f(v1[3]) + bf2f(v2[3]) + bf2f(v3[3])
        + bf2f(v4[3]) + bf2f(v5[3]) + bf2f(v6[3]) + bf2f(v7[3]);
  }
  for (; i + 4 <= deg; i += 4) {
    int n0 = he_list[s + i + 0];
    int n1 = he_list[s + i + 1];
    int n2 = he_list[s + i + 2];
    int n3 = he_list[s + i + 3];
    ushort4v v0 = ((const ushort4v*)(xt + (size_t)n0 * D))[lane];
    ushort4v v1 = ((const ushort4v*)(xt + (size_t)n1 * D))[lane];
    ushort4v v2 = ((const ushort4v*)(xt + (size_t)n2 * D))[lane];
    ushort4v v3 = ((const ushort4v*)(xt + (size_t)n3 * D))[lane];
    a0 += bf2f(v0[0]) + bf2f(v1[0]) + bf2f(v2[0]) + bf2f(v3[0]);
    a1 += bf2f(v0[1]) + bf2f(v1[1]) + bf2f(v2[1]) + bf2f(v3[1]);
    a2 += bf2f(v0[2]) + bf2f(v1[2]) + bf2f(v2[2]) + bf2f(v3[2]);
    a3 += bf2f(v0[3]) + bf2f(v1[3]) + bf2f(v2[3]) + bf2f(v3[3]);
  }
  for (; i < deg; ++i) {
    int n = he_list[s + i];
    ushort4v v = ((const ushort4v*)(xt + (size_t)n * D))[lane];
    a0 += bf2f(v[0]); a1 += bf2f(v[1]); a2 += bf2f(v[2]); a3 += bf2f(v[3]);
  }
  float inv = 1.0f / ((float)deg + MEAN_EPS);
  ushort4v o;
  o[0] = f2bf(a0 * inv); o[1] = f2bf(a1 * inv);
  o[2] = f2bf(a2 * inv); o[3] = f2bf(a3 * inv);
  ((ushort4v*)(he_mean + (size_t)e * D))[lane] = o;
}

// ---------------------------------------------------------------------------
// Fused: gather hyperedges -> node mean, + xt residual, LayerNorm, LeakyReLU,
// optional outer residual. One wave per node. O_F32 selects output dtype.
// ---------------------------------------------------------------------------
template <int O_F32>
__global__ __launch_bounds__(256) void finalize_k(
    const unsigned short* __restrict__ he_feat, const int* __restrict__ n_start,
    const int* __restrict__ n_deg, const int* __restrict__ n_list,
    const unsigned short* __restrict__ xt, const float* __restrict__ g,
    const float* __restrict__ b, const unsigned short* __restrict__ res,
    void* __restrict__ outv, int add_res) {
  int node = blockIdx.x * 4 + (threadIdx.x >> 6);
  if (node >= N_NODES) return;
  int lane = threadIdx.x & 63;
  int s = n_start[node];
  int deg = n_deg[node];

  float a0 = 0.f, a1 = 0.f, a2 = 0.f, a3 = 0.f;
  int i = 0;
  for (; i + 4 <= deg; i += 4) {
    int e0 = n_list[s + i + 0];
    int e1 = n_list[s + i + 1];
    int e2 = n_list[s + i + 2];
    int e3 = n_list[s + i + 3];
    ushort4v v0 = ((const ushort4v*)(he_feat + (size_t)e0 * D))[lane];
    ushort4v v1 = ((const ushort4v*)(he_feat + (size_t)e1 * D))[lane];
    ushort4v v2 = ((const ushort4v*)(he_feat + (size_t)e2 * D))[lane];
    ushort4v v3 = ((const ushort4v*)(he_feat + (size_t)e3 * D))[lane];
    a0 += bf2f(v0[0]) + bf2f(v1[0]) + bf2f(v2[0]) + bf2f(v3[0]);
    a1 += bf2f(v0[1]) + bf2f(v1[1]) + bf2f(v2[1]) + bf2f(v3[1]);
    a2 += bf2f(v0[2]) + bf2f(v1[2]) + bf2f(v2[2]) + bf2f(v3[2]);
    a3 += bf2f(v0[3]) + bf2f(v1[3]) + bf2f(v2[3]) + bf2f(v3[3]);
  }
  for (; i < deg; ++i) {
    int e = n_list[s + i];
    ushort4v v = ((const ushort4v*)(he_feat + (size_t)e * D))[lane];
    a0 += bf2f(v[0]); a1 += bf2f(v[1]); a2 += bf2f(v[2]); a3 += bf2f(v[3]);
  }
  float inv = deg > 0 ? 1.0f / (float)deg : 0.0f;

  ushort4v xv = ((const ushort4v*)(xt + (size_t)node * D))[lane];
  float h0 = a0 * inv + bf2f(xv[0]);
  float h1 = a1 * inv + bf2f(xv[1]);
  float h2 = a2 * inv + bf2f(xv[2]);
  float h3 = a3 * inv + bf2f(xv[3]);

  float sum = h0 + h1 + h2 + h3;
  float ss  = h0 * h0 + h1 * h1 + h2 * h2 + h3 * h3;
  #pragma unroll
  for (int o = 32; o > 0; o >>= 1) {
    sum += __shfl_xor(sum, o, 64);
    ss  += __shfl_xor(ss, o, 64);
  }
  float mu  = sum * (1.0f / D);
  float var = ss * (1.0f / D) - mu * mu;
  float rstd = rsqrtf(var + LN_EPS);

  float4 gv = ((const float4*)g)[lane];
  float4 bv = ((const float4*)b)[lane];

  float o0 = (h0 - mu) * rstd * gv.x + bv.x;
  float o1 = (h1 - mu) * rstd * gv.y + bv.y;
  float o2 = (h2 - mu) * rstd * gv.z + bv.z;
  float o3 = (h3 - mu) * rstd * gv.w + bv.w;
  o0 = o0 >= 0.f ? o0 : o0 * SLOPE;
  o1 = o1 >= 0.f ? o1 : o1 * SLOPE;
  o2 = o2 >= 0.f ? o2 : o2 * SLOPE;
  o3 = o3 >= 0.f ? o3 : o3 * SLOPE;

  if (add_res) {
    ushort4v rv = ((const ushort4v*)(res + (size_t)node * D))[lane];
    o0 += bf2f(rv[0]); o1 += bf2f(rv[1]); o2 += bf2f(rv[2]); o3 += bf2f(rv[3]);
  }

  if (O_F32) {
    ((float4*)((float*)outv + (size_t)node * D))[lane] = make_float4(o0, o1, o2, o3);
  } else {
    ushort4v ov;
    ov[0] = f2bf(o0); ov[1] = f2bf(o1); ov[2] = f2bf(o2); ov[3] = f2bf(o3);
    ((ushort4v*)((unsigned short*)outv + (size_t)node * D))[lane] = ov;
  }
}

// ---------------------------------------------------------------------------
extern "C" void kernel_launch(void* const* d_in, const int* in_sizes, int n_in,
                              void* d_out, int out_size, void* d_ws, size_t ws_size,
                              hipStream_t stream) {
  const float* x       = (const float*)d_in[0];
  const float* node_W  = (const float*)d_in[1];  // [2,256,256]
  const float* node_b  = (const float*)d_in[2];  // [2,256]
  const float* he_W    = (const float*)d_in[3];
  const float* he_b    = (const float*)d_in[4];
  const float* ln_g    = (const float*)d_in[5];
  const float* ln_b    = (const float*)d_in[6];
  const float* hw      = (const float*)d_in[7];  // [25000]
  const int*   node_idx = (const int*)d_in[8];
  const int*   he_idx   = (const int*)d_in[9];

  // Workspace layout (bf16 intermediates; GEMM inputs padded to 64-row mult).
  unsigned short* x_bf    = (unsigned short*)d_ws;          // N_PAD*256
  unsigned short* out_bf  = x_bf + (size_t)N_PAD * D;       // N_PAD*256
  unsigned short* he_mean = out_bf + (size_t)N_PAD * D;     // N_HE_PAD*256
  unsigned short* xt      = he_mean + (size_t)N_HE_PAD * D; // 100000*256
  unsigned short* he_buf  = xt + (size_t)N_NODES * D;       // 25000*256
  unsigned short* Wt_all  = he_buf + (size_t)N_HE * D;      // 4*65536
  int* he_deg   = (int*)(Wt_all + 4 * 65536);               // 25000
  int* n_deg    = he_deg + N_HE;                            // 100000
  int* totals   = n_deg + N_NODES;                          // 2
  int* he_start = totals + 2;                               // 25000
  int* he_cur   = he_start + N_HE;                          // 25000
  int* n_start  = he_cur + N_HE;                            // 100000
  int* n_cur    = n_start + N_NODES;                        // 100000
  int* he_list  = n_cur + N_NODES;                          // 400000
  int* n_list   = he_list + N_CONN;                         // 400000

  // --- x -> bf16 ---
  conv_x<<<2048, 256, 0, stream>>>(x, x_bf, N_NODES * D / 8);

  // --- Weight convert+transpose (all 4 matrices, one dispatch) ---
  convert_w<<<64, 256, 0, stream>>>(node_W, he_W, Wt_all);

  // --- Build adjacency (every call; indices are constant inputs) ---
  hipMemsetAsync(he_deg, 0, (size_t)(N_HE + N_NODES + 2) * sizeof(int), stream);
  hist_kernel<<<(N_CONN + 255) / 256, 256, 0, stream>>>(node_idx, he_idx, he_deg, n_deg);
  alloc_kernel<<<(N_NODES + 255) / 256, 256, 0, stream>>>(
      he_deg, n_deg, totals, he_start, he_cur, n_start, n_cur);
  fill_kernel<<<(N_CONN + 255) / 256, 256, 0, stream>>>(
      node_idx, he_idx, he_cur, n_cur, he_list, n_list);

  const int ntiles_node = N_PAD / 64;    // 1563
  const int ntiles_he   = N_HE_PAD / 64; // 391

  for (int l = 0; l < 2; ++l) {
    const unsigned short* Wtn = Wt_all + (size_t)l * 65536;
    const unsigned short* Wte = Wt_all + (size_t)(2 + l) * 65536;
    const float* bn = node_b + (size_t)l * D;
    const float* be = he_b + (size_t)l * D;
    const float* g  = ln_g + (size_t)l * D;
    const float* bb = ln_b + (size_t)l * D;

    gemm_pipe<<<512, 512, 0, stream>>>(
        (l == 0) ? x_bf : out_bf, Wtn, bn, nullptr, xt, N_NODES, ntiles_node);
    gather_he<<<(N_HE + 3) / 4, 256, 0, stream>>>(
        xt, he_start, he_deg, he_list, he_mean);
    gemm_pipe<<<ntiles_he, 512, 0, stream>>>(
        he_mean, Wte, be, hw, he_buf, N_HE, ntiles_he);
    if (l == 0) {
      finalize_k<0><<<(N_NODES + 3) / 4, 256, 0, stream>>>(
          he_buf, n_start, n_deg, n_list, xt, g, bb, nullptr, out_bf, 0);
    } else {
      finalize_k<1><<<(N_NODES + 3) / 4, 256, 0, stream>>>(
          he_buf, n_start, n_deg, n_list, xt, g, bb, out_bf, d_out, 1);
    }
  }
}

// Round 13
// 425.077 us; speedup vs baseline: 1.0602x; 1.0602x over previous
//
#include <hip/hip_runtime.h>

#define D 256
#define N_NODES 100000
#define N_HE 25000
#define N_CONN 400000
#define N_PAD 100032  // N_NODES padded to tile multiple for DMA over-read

constexpr float MEAN_EPS = 1e-8f;
constexpr float LN_EPS   = 1e-5f;
constexpr float SLOPE    = 0.2f;

typedef __attribute__((ext_vector_type(8))) short short8;
typedef __attribute__((ext_vector_type(4))) float f32x4;
typedef __attribute__((ext_vector_type(16))) float f32x16;
typedef __attribute__((ext_vector_type(4))) unsigned short ushort4v;

static __device__ __forceinline__ unsigned short f2bf(float f) {
  unsigned int u = __builtin_bit_cast(unsigned int, f);
  u = (u + 0x7FFFu + ((u >> 16) & 1u)) >> 16;
  return (unsigned short)u;
}
static __device__ __forceinline__ float bf2f(unsigned short u) {
  return __builtin_bit_cast(float, (unsigned int)u << 16);
}

// ---------------------------------------------------------------------------
// x (fp32) -> bf16
// ---------------------------------------------------------------------------
__global__ __launch_bounds__(256) void conv_x(
    const float* __restrict__ in, unsigned short* __restrict__ out, int n8) {
  int i = blockIdx.x * 256 + threadIdx.x;
  int stride = gridDim.x * 256;
  for (; i < n8; i += stride) {
    float4 a = ((const float4*)in)[(size_t)i * 2];
    float4 b = ((const float4*)in)[(size_t)i * 2 + 1];
    short8 o;
    o[0] = (short)f2bf(a.x); o[1] = (short)f2bf(a.y);
    o[2] = (short)f2bf(a.z); o[3] = (short)f2bf(a.w);
    o[4] = (short)f2bf(b.x); o[5] = (short)f2bf(b.y);
    o[6] = (short)f2bf(b.z); o[7] = (short)f2bf(b.w);
    ((short8*)out)[i] = o;
  }
}

// ---------------------------------------------------------------------------
// Adjacency build (indices are constant inputs; rebuilt every call)
// ---------------------------------------------------------------------------
__global__ __launch_bounds__(256) void hist_kernel(
    const int* __restrict__ node_idx, const int* __restrict__ he_idx,
    int* __restrict__ he_deg, int* __restrict__ n_deg) {
  int c = blockIdx.x * 256 + threadIdx.x;
  if (c < N_CONN) {
    atomicAdd(&he_deg[he_idx[c]], 1);
    atomicAdd(&n_deg[node_idx[c]], 1);
  }
}

__global__ __launch_bounds__(256) void alloc_kernel(
    const int* __restrict__ he_deg, const int* __restrict__ n_deg,
    int* __restrict__ totals,
    int* __restrict__ he_start, int* __restrict__ he_cur,
    int* __restrict__ n_start, int* __restrict__ n_cur) {
  int i = blockIdx.x * 256 + threadIdx.x;
  if (i < N_HE) {
    int s = atomicAdd(&totals[0], he_deg[i]);
    he_start[i] = s;
    he_cur[i] = s;
  }
  if (i < N_NODES) {
    int s = atomicAdd(&totals[1], n_deg[i]);
    n_start[i] = s;
    n_cur[i] = s;
  }
}

__global__ __launch_bounds__(256) void fill_kernel(
    const int* __restrict__ node_idx, const int* __restrict__ he_idx,
    int* __restrict__ he_cur, int* __restrict__ n_cur,
    int* __restrict__ he_list, int* __restrict__ n_list) {
  int c = blockIdx.x * 256 + threadIdx.x;
  if (c < N_CONN) {
    int n = node_idx[c];
    int e = he_idx[c];
    int p = atomicAdd(&he_cur[e], 1);
    he_list[p] = n;
    int q = atomicAdd(&n_cur[n], 1);
    n_list[q] = e;
  }
}

// ---------------------------------------------------------------------------
// Weight convert+transpose: Wt[n][k] = bf16(W[k][n]).
// ---------------------------------------------------------------------------
__global__ __launch_bounds__(256) void convert_w(
    const float* __restrict__ Wnode, const float* __restrict__ Whe,
    unsigned short* __restrict__ Wt) {
  int m = blockIdx.x >> 4;
  int tile = blockIdx.x & 15;
  int k0 = (tile >> 2) * 64, n0 = (tile & 3) * 64;
  const float* Win = (m < 2) ? (Wnode + (size_t)m * 65536)
                             : (Whe + (size_t)(m - 2) * 65536);
  unsigned short* Wout = Wt + (size_t)m * 65536;
  __shared__ unsigned short T[64][65];
  int t = threadIdx.x;
  int r = t >> 6, c = t & 63;
  #pragma unroll 4
  for (int i = 0; i < 16; ++i) {
    int kr = i * 4 + r;
    T[kr][c] = f2bf(Win[(size_t)(k0 + kr) * 256 + n0 + c]);
  }
  __syncthreads();
  #pragma unroll 4
  for (int i = 0; i < 16; ++i) {
    int nr = i * 4 + r;
    Wout[(size_t)(n0 + nr) * 256 + k0 + c] = T[c][nr];
  }
}

// ---------------------------------------------------------------------------
// GEMM: bf16 A staged via global_load_lds width=16 (A/B-validated winner).
// Double-buffered (2x32KB), grid-stride; one __syncthreads per tile.
// ---------------------------------------------------------------------------
__global__ __launch_bounds__(512, 4) void gemm_pipe(
    const unsigned short* __restrict__ A, const unsigned short* __restrict__ Wt,
    const float* __restrict__ bias, unsigned short* __restrict__ out,
    int M, int ntiles) {
  __shared__ unsigned short As[2][64 * 256];  // 2 x 32 KB
  const int t = threadIdx.x;
  const int wave = t >> 6, lane = t & 63;
  const int l31 = lane & 31, lhi = lane >> 5;
  const int colbase = wave * 32;

  // ---- preload + pin B ----
  f32x4 B[16];
  {
    const unsigned short* bp = Wt + (size_t)(colbase + l31) * 256 + lhi * 8;
    #pragma unroll
    for (int kc = 0; kc < 16; ++kc)
      B[kc] = *(const f32x4*)(bp + kc * 16);
  }
  #pragma unroll
  for (int kc = 0; kc < 16; ++kc)
    asm volatile("" : "+v"(B[kc]));
  float biasv = bias[colbase + l31];

  // Per-lane swizzled source offsets (ushort units within a 64x256 tile).
  int goff[4];
  #pragma unroll
  for (int i = 0; i < 4; ++i) {
    int c = i * 512 + t;
    int row = c >> 5, s = c & 31;
    int ss = (s & 24) | ((s & 7) ^ (row & 7));
    goff[i] = row * 256 + ss * 8;
  }

  // ---- prologue: stage first tile into buf 0 ----
  {
    const unsigned short* base = A + (size_t)blockIdx.x * 64 * 256;
    #pragma unroll
    for (int i = 0; i < 4; ++i) {
      __builtin_amdgcn_global_load_lds(
          (const __attribute__((address_space(1))) void*)(base + goff[i]),
          (__attribute__((address_space(3))) void*)((char*)As[0] + i * 8192 + wave * 1024),
          16, 0, 0);
    }
  }

  int cur = 0;
  for (int tile = blockIdx.x; tile < ntiles; tile += gridDim.x) {
    __syncthreads();  // drains vmcnt -> As[cur] DMA complete; prev compute done

    const int next = tile + gridDim.x;
    if (next < ntiles) {
      const unsigned short* base = A + (size_t)next * 64 * 256;
      #pragma unroll
      for (int i = 0; i < 4; ++i) {
        __builtin_amdgcn_global_load_lds(
            (const __attribute__((address_space(1))) void*)(base + goff[i]),
            (__attribute__((address_space(3))) void*)((char*)As[cur ^ 1] + i * 8192 + wave * 1024),
            16, 0, 0);
      }
    }

    // ---- compute current tile ----
    const int row0 = tile * 64;
    const char* Ab = (const char*)As[cur];
    f32x16 acc0 = (f32x16)0.f, acc1 = (f32x16)0.f;
    #pragma unroll
    for (int kc = 0; kc < 16; ++kc) {
      unsigned int ad0 = (unsigned)(l31 * 512 + kc * 32 + lhi * 16) ^ (unsigned)((l31 & 7) << 4);
      short8 a0 = *(const short8*)(Ab + ad0);
      unsigned int ad1 = (unsigned)((32 + l31) * 512 + kc * 32 + lhi * 16) ^ (unsigned)((l31 & 7) << 4);
      short8 a1 = *(const short8*)(Ab + ad1);
      short8 b = __builtin_bit_cast(short8, B[kc]);
      acc0 = __builtin_amdgcn_mfma_f32_32x32x16_bf16(a0, b, acc0, 0, 0, 0);
      acc1 = __builtin_amdgcn_mfma_f32_32x32x16_bf16(a1, b, acc1, 0, 0, 0);
    }

    const int col = colbase + l31;
    #pragma unroll
    for (int rt = 0; rt < 2; ++rt) {
      #pragma unroll
      for (int reg = 0; reg < 16; ++reg) {
        int row = (reg & 3) + 8 * (reg >> 2) + 4 * lhi;
        int grow = row0 + rt * 32 + row;
        if (grow < M) {
          float v = ((rt == 0) ? acc0[reg] : acc1[reg]) + biasv;
          out[(size_t)grow * D + col] = f2bf(v);
        }
      }
    }
    cur ^= 1;
  }
}

// ---------------------------------------------------------------------------
// Fused: gather nodes -> hyperedge mean (into swizzled LDS A-tile), then
// 32x32x16 MFMA with pinned-B: he_out = (mean @ We + be) * hw.  bf16 in/out.
// (round-11 version — fused beat the split in the round-12 A/B)
// ---------------------------------------------------------------------------
__global__ __launch_bounds__(512, 4) void he_fused(
    const unsigned short* __restrict__ xt, const int* __restrict__ he_start,
    const int* __restrict__ he_deg, const int* __restrict__ he_list,
    const unsigned short* __restrict__ Wt, const float* __restrict__ bias,
    const float* __restrict__ hwp, unsigned short* __restrict__ he_out) {
  __shared__ unsigned short As[64 * 256];  // 32 KB
  const int t = threadIdx.x;
  const int wave = t >> 6, lane = t & 63;
  const int l31 = lane & 31, lhi = lane >> 5;
  const int colbase = wave * 32;

  // ---- preload + pin B ----
  f32x4 B[16];
  {
    const unsigned short* bp = Wt + (size_t)(colbase + l31) * 256 + lhi * 8;
    #pragma unroll
    for (int kc = 0; kc < 16; ++kc)
      B[kc] = *(const f32x4*)(bp + kc * 16);
  }
  #pragma unroll
  for (int kc = 0; kc < 16; ++kc)
    asm volatile("" : "+v"(B[kc]));
  float biasv = bias[colbase + l31];

  // ---- gather phase: wave gathers rows wave*8 .. wave*8+7 ----
  const int e0 = blockIdx.x * 64;
  for (int j = 0; j < 8; ++j) {
    int row = wave * 8 + j;
    int e = e0 + row;
    float a0 = 0.f, a1 = 0.f, a2 = 0.f, a3 = 0.f;
    float invv = 0.f;
    if (e < N_HE) {
      int s = he_start[e];
      int deg = he_deg[e];
      int i = 0;
      for (; i + 8 <= deg; i += 8) {
        int n0 = he_list[s + i + 0];
        int n1 = he_list[s + i + 1];
        int n2 = he_list[s + i + 2];
        int n3 = he_list[s + i + 3];
        int n4 = he_list[s + i + 4];
        int n5 = he_list[s + i + 5];
        int n6 = he_list[s + i + 6];
        int n7 = he_list[s + i + 7];
        ushort4v v0 = ((const ushort4v*)(xt + (size_t)n0 * D))[lane];
        ushort4v v1 = ((const ushort4v*)(xt + (size_t)n1 * D))[lane];
        ushort4v v2 = ((const ushort4v*)(xt + (size_t)n2 * D))[lane];
        ushort4v v3 = ((const ushort4v*)(xt + (size_t)n3 * D))[lane];
        ushort4v v4 = ((const ushort4v*)(xt + (size_t)n4 * D))[lane];
        ushort4v v5 = ((const ushort4v*)(xt + (size_t)n5 * D))[lane];
        ushort4v v6 = ((const ushort4v*)(xt + (size_t)n6 * D))[lane];
        ushort4v v7 = ((const ushort4v*)(xt + (size_t)n7 * D))[lane];
        a0 += bf2f(v0[0]) + bf2f(v1[0]) + bf2f(v2[0]) + bf2f(v3[0])
            + bf2f(v4[0]) + bf2f(v5[0]) + bf2f(v6[0]) + bf2f(v7[0]);
        a1 += bf2f(v0[1]) + bf2f(v1[1]) + bf2f(v2[1]) + bf2f(v3[1])
            + bf2f(v4[1]) + bf2f(v5[1]) + bf2f(v6[1]) + bf2f(v7[1]);
        a2 += bf2f(v0[2]) + bf2f(v1[2]) + bf2f(v2[2]) + bf2f(v3[2])
            + bf2f(v4[2]) + bf2f(v5[2]) + bf2f(v6[2]) + bf2f(v7[2]);
        a3 += bf2f(v0[3]) + bf2f(v1[3]) + bf2f(v2[3]) + bf2f(v3[3])
            + bf2f(v4[3]) + bf2f(v5[3]) + bf2f(v6[3]) + bf2f(v7[3]);
      }
      for (; i + 4 <= deg; i += 4) {
        int n0 = he_list[s + i + 0];
        int n1 = he_list[s + i + 1];
        int n2 = he_list[s + i + 2];
        int n3 = he_list[s + i + 3];
        ushort4v v0 = ((const ushort4v*)(xt + (size_t)n0 * D))[lane];
        ushort4v v1 = ((const ushort4v*)(xt + (size_t)n1 * D))[lane];
        ushort4v v2 = ((const ushort4v*)(xt + (size_t)n2 * D))[lane];
        ushort4v v3 = ((const ushort4v*)(xt + (size_t)n3 * D))[lane];
        a0 += bf2f(v0[0]) + bf2f(v1[0]) + bf2f(v2[0]) + bf2f(v3[0]);
        a1 += bf2f(v0[1]) + bf2f(v1[1]) + bf2f(v2[1]) + bf2f(v3[1]);
        a2 += bf2f(v0[2]) + bf2f(v1[2]) + bf2f(v2[2]) + bf2f(v3[2]);
        a3 += bf2f(v0[3]) + bf2f(v1[3]) + bf2f(v2[3]) + bf2f(v3[3]);
      }
      for (; i < deg; ++i) {
        int n = he_list[s + i];
        ushort4v v = ((const ushort4v*)(xt + (size_t)n * D))[lane];
        a0 += bf2f(v[0]); a1 += bf2f(v[1]); a2 += bf2f(v[2]); a3 += bf2f(v[3]);
      }
      invv = 1.0f / ((float)deg + MEAN_EPS);
    }
    ushort4v o;
    o[0] = f2bf(a0 * invv); o[1] = f2bf(a1 * invv);
    o[2] = f2bf(a2 * invv); o[3] = f2bf(a3 * invv);
    unsigned int byte = (unsigned)(row * 512 + lane * 8) ^ (unsigned)((row & 7) << 4);
    *(ushort4v*)((char*)As + byte) = o;
  }
  __syncthreads();

  // ---- MFMA phase ----
  f32x16 acc0 = (f32x16)0.f, acc1 = (f32x16)0.f;
  #pragma unroll
  for (int kc = 0; kc < 16; ++kc) {
    unsigned int ad0 = (unsigned)(l31 * 512 + kc * 32 + lhi * 16) ^ (unsigned)((l31 & 7) << 4);
    short8 a0 = *(const short8*)((const char*)As + ad0);
    unsigned int ad1 = (unsigned)((32 + l31) * 512 + kc * 32 + lhi * 16) ^ (unsigned)((l31 & 7) << 4);
    short8 a1 = *(const short8*)((const char*)As + ad1);
    short8 b = __builtin_bit_cast(short8, B[kc]);
    acc0 = __builtin_amdgcn_mfma_f32_32x32x16_bf16(a0, b, acc0, 0, 0, 0);
    acc1 = __builtin_amdgcn_mfma_f32_32x32x16_bf16(a1, b, acc1, 0, 0, 0);
  }

  const int col = colbase + l31;
  #pragma unroll
  for (int rt = 0; rt < 2; ++rt) {
    #pragma unroll
    for (int reg = 0; reg < 16; ++reg) {
      int row = (reg & 3) + 8 * (reg >> 2) + 4 * lhi;
      int grow = e0 + rt * 32 + row;
      if (grow < N_HE) {
        float v = (((rt == 0) ? acc0[reg] : acc1[reg]) + biasv) * hwp[grow];
        he_out[(size_t)grow * D + col] = f2bf(v);
      }
    }
  }
}

// ---------------------------------------------------------------------------
// Fused finalize, 32-lane-per-node (2 nodes/wave, 8/block): gather he -> mean,
// + xt, LayerNorm (5-round shfl within 32-lane group), LeakyReLU, opt residual.
// 16 B/lane loads throughout.
// ---------------------------------------------------------------------------
template <int O_F32>
__global__ __launch_bounds__(256) void finalize_k(
    const unsigned short* __restrict__ he_feat, const int* __restrict__ n_start,
    const int* __restrict__ n_deg, const int* __restrict__ n_list,
    const unsigned short* __restrict__ xt, const float* __restrict__ g,
    const float* __restrict__ b, const unsigned short* __restrict__ res,
    void* __restrict__ outv, int add_res) {
  int node = blockIdx.x * 8 + (threadIdx.x >> 5);
  if (node >= N_NODES) return;
  int lane = threadIdx.x & 31;  // 32 lanes x 16 B = 512 B row
  int s = n_start[node];
  int deg = n_deg[node];

  float a[8];
  #pragma unroll
  for (int k = 0; k < 8; ++k) a[k] = 0.f;

  int i = 0;
  for (; i + 4 <= deg; i += 4) {
    int e0 = n_list[s + i + 0];
    int e1 = n_list[s + i + 1];
    int e2 = n_list[s + i + 2];
    int e3 = n_list[s + i + 3];
    short8 v0 = ((const short8*)(he_feat + (size_t)e0 * D))[lane];
    short8 v1 = ((const short8*)(he_feat + (size_t)e1 * D))[lane];
    short8 v2 = ((const short8*)(he_feat + (size_t)e2 * D))[lane];
    short8 v3 = ((const short8*)(he_feat + (size_t)e3 * D))[lane];
    #pragma unroll
    for (int k = 0; k < 8; ++k)
      a[k] += bf2f((unsigned short)v0[k]) + bf2f((unsigned short)v1[k])
            + bf2f((unsigned short)v2[k]) + bf2f((unsigned short)v3[k]);
  }
  for (; i < deg; ++i) {
    int e = n_list[s + i];
    short8 v = ((const short8*)(he_feat + (size_t)e * D))[lane];
    #pragma unroll
    for (int k = 0; k < 8; ++k) a[k] += bf2f((unsigned short)v[k]);
  }
  float inv = deg > 0 ? 1.0f / (float)deg : 0.0f;

  short8 xv = ((const short8*)(xt + (size_t)node * D))[lane];
  float h[8];
  #pragma unroll
  for (int k = 0; k < 8; ++k) h[k] = a[k] * inv + bf2f((unsigned short)xv[k]);

  float sum = 0.f, ss = 0.f;
  #pragma unroll
  for (int k = 0; k < 8; ++k) { sum += h[k]; ss += h[k] * h[k]; }
  #pragma unroll
  for (int o = 16; o > 0; o >>= 1) {  // masks <32: stays within the group
    sum += __shfl_xor(sum, o);
    ss  += __shfl_xor(ss, o);
  }
  float mu  = sum * (1.0f / D);
  float var = ss * (1.0f / D) - mu * mu;
  float rstd = rsqrtf(var + LN_EPS);

  float4 gv0 = ((const float4*)g)[lane * 2];
  float4 gv1 = ((const float4*)g)[lane * 2 + 1];
  float4 bv0 = ((const float4*)b)[lane * 2];
  float4 bv1 = ((const float4*)b)[lane * 2 + 1];
  float gg[8] = {gv0.x, gv0.y, gv0.z, gv0.w, gv1.x, gv1.y, gv1.z, gv1.w};
  float bb[8] = {bv0.x, bv0.y, bv0.z, bv0.w, bv1.x, bv1.y, bv1.z, bv1.w};

  float o8[8];
  #pragma unroll
  for (int k = 0; k < 8; ++k) {
    float v = (h[k] - mu) * rstd * gg[k] + bb[k];
    o8[k] = v >= 0.f ? v : v * SLOPE;
  }

  if (add_res) {
    short8 rv = ((const short8*)(res + (size_t)node * D))[lane];
    #pragma unroll
    for (int k = 0; k < 8; ++k) o8[k] += bf2f((unsigned short)rv[k]);
  }

  if (O_F32) {
    float* out = (float*)outv + (size_t)node * D;
    ((float4*)out)[lane * 2]     = make_float4(o8[0], o8[1], o8[2], o8[3]);
    ((float4*)out)[lane * 2 + 1] = make_float4(o8[4], o8[5], o8[6], o8[7]);
  } else {
    short8 ov;
    #pragma unroll
    for (int k = 0; k < 8; ++k) ov[k] = (short)f2bf(o8[k]);
    ((short8*)((unsigned short*)outv + (size_t)node * D))[lane] = ov;
  }
}

// ---------------------------------------------------------------------------
extern "C" void kernel_launch(void* const* d_in, const int* in_sizes, int n_in,
                              void* d_out, int out_size, void* d_ws, size_t ws_size,
                              hipStream_t stream) {
  const float* x       = (const float*)d_in[0];
  const float* node_W  = (const float*)d_in[1];  // [2,256,256]
  const float* node_b  = (const float*)d_in[2];  // [2,256]
  const float* he_W    = (const float*)d_in[3];
  const float* he_b    = (const float*)d_in[4];
  const float* ln_g    = (const float*)d_in[5];
  const float* ln_b    = (const float*)d_in[6];
  const float* hw      = (const float*)d_in[7];  // [25000]
  const int*   node_idx = (const int*)d_in[8];
  const int*   he_idx   = (const int*)d_in[9];

  // Workspace layout (bf16 intermediates; GEMM inputs padded to N_PAD rows).
  unsigned short* x_bf   = (unsigned short*)d_ws;           // N_PAD*256
  unsigned short* out_bf = x_bf + (size_t)N_PAD * D;        // N_PAD*256
  unsigned short* xt     = out_bf + (size_t)N_PAD * D;      // 100000*256
  unsigned short* he_buf = xt + (size_t)N_NODES * D;        // 25000*256
  unsigned short* Wt_all = he_buf + (size_t)N_HE * D;       // 4*65536
  int* he_deg   = (int*)(Wt_all + 4 * 65536);               // 25000
  int* n_deg    = he_deg + N_HE;                            // 100000
  int* totals   = n_deg + N_NODES;                          // 2
  int* he_start = totals + 2;                               // 25000
  int* he_cur   = he_start + N_HE;                          // 25000
  int* n_start  = he_cur + N_HE;                            // 100000
  int* n_cur    = n_start + N_NODES;                        // 100000
  int* he_list  = n_cur + N_NODES;                          // 400000
  int* n_list   = he_list + N_CONN;                         // 400000

  // --- x -> bf16 ---
  conv_x<<<2048, 256, 0, stream>>>(x, x_bf, N_NODES * D / 8);

  // --- Weight convert+transpose (all 4 matrices, one dispatch) ---
  convert_w<<<64, 256, 0, stream>>>(node_W, he_W, Wt_all);

  // --- Build adjacency (every call; indices are constant inputs) ---
  hipMemsetAsync(he_deg, 0, (size_t)(N_HE + N_NODES + 2) * sizeof(int), stream);
  hist_kernel<<<(N_CONN + 255) / 256, 256, 0, stream>>>(node_idx, he_idx, he_deg, n_deg);
  alloc_kernel<<<(N_NODES + 255) / 256, 256, 0, stream>>>(
      he_deg, n_deg, totals, he_start, he_cur, n_start, n_cur);
  fill_kernel<<<(N_CONN + 255) / 256, 256, 0, stream>>>(
      node_idx, he_idx, he_cur, n_cur, he_list, n_list);

  const int ntiles_node = N_PAD / 64;        // 1563
  const int nblk_he     = (N_HE + 63) / 64;  // 391

  for (int l = 0; l < 2; ++l) {
    const unsigned short* Wtn = Wt_all + (size_t)l * 65536;
    const unsigned short* Wte = Wt_all + (size_t)(2 + l) * 65536;
    const float* bn = node_b + (size_t)l * D;
    const float* be = he_b + (size_t)l * D;
    const float* g  = ln_g + (size_t)l * D;
    const float* bb = ln_b + (size_t)l * D;

    gemm_pipe<<<512, 512, 0, stream>>>(
        (l == 0) ? x_bf : out_bf, Wtn, bn, xt, N_NODES, ntiles_node);
    he_fused<<<nblk_he, 512, 0, stream>>>(
        xt, he_start, he_deg, he_list, Wte, be, hw, he_buf);
    if (l == 0) {
      finalize_k<0><<<(N_NODES + 7) / 8, 256, 0, stream>>>(
          he_buf, n_start, n_deg, n_list, xt, g, bb, nullptr, out_bf, 0);
    } else {
      finalize_k<1><<<(N_NODES + 7) / 8, 256, 0, stream>>>(
          he_buf, n_start, n_deg, n_list, xt, g, bb, out_bf, d_out, 1);
    }
  }
}

// Round 14
// 419.031 us; speedup vs baseline: 1.0755x; 1.0144x over previous
//
#include <hip/hip_runtime.h>

#define D 256
#define N_NODES 100000
#define N_HE 25000
#define N_CONN 400000
#define N_PAD 100032  // N_NODES padded to tile multiple for DMA over-read

constexpr float MEAN_EPS = 1e-8f;
constexpr float LN_EPS   = 1e-5f;
constexpr float SLOPE    = 0.2f;

typedef __attribute__((ext_vector_type(8))) short short8;
typedef __attribute__((ext_vector_type(4))) float f32x4;
typedef __attribute__((ext_vector_type(16))) float f32x16;
typedef __attribute__((ext_vector_type(4))) unsigned short ushort4v;

static __device__ __forceinline__ unsigned short f2bf(float f) {
  unsigned int u = __builtin_bit_cast(unsigned int, f);
  u = (u + 0x7FFFu + ((u >> 16) & 1u)) >> 16;
  return (unsigned short)u;
}
static __device__ __forceinline__ float bf2f(unsigned short u) {
  return __builtin_bit_cast(float, (unsigned int)u << 16);
}

// ---------------------------------------------------------------------------
// x (fp32) -> bf16
// ---------------------------------------------------------------------------
__global__ __launch_bounds__(256) void conv_x(
    const float* __restrict__ in, unsigned short* __restrict__ out, int n8) {
  int i = blockIdx.x * 256 + threadIdx.x;
  int stride = gridDim.x * 256;
  for (; i < n8; i += stride) {
    float4 a = ((const float4*)in)[(size_t)i * 2];
    float4 b = ((const float4*)in)[(size_t)i * 2 + 1];
    short8 o;
    o[0] = (short)f2bf(a.x); o[1] = (short)f2bf(a.y);
    o[2] = (short)f2bf(a.z); o[3] = (short)f2bf(a.w);
    o[4] = (short)f2bf(b.x); o[5] = (short)f2bf(b.y);
    o[6] = (short)f2bf(b.z); o[7] = (short)f2bf(b.w);
    ((short8*)out)[i] = o;
  }
}

// ---------------------------------------------------------------------------
// Adjacency build (indices are constant inputs; rebuilt every call)
// ---------------------------------------------------------------------------
__global__ __launch_bounds__(256) void hist_kernel(
    const int* __restrict__ node_idx, const int* __restrict__ he_idx,
    int* __restrict__ he_deg, int* __restrict__ n_deg) {
  int c = blockIdx.x * 256 + threadIdx.x;
  if (c < N_CONN) {
    atomicAdd(&he_deg[he_idx[c]], 1);
    atomicAdd(&n_deg[node_idx[c]], 1);
  }
}

__global__ __launch_bounds__(256) void alloc_kernel(
    const int* __restrict__ he_deg, const int* __restrict__ n_deg,
    int* __restrict__ totals,
    int* __restrict__ he_start, int* __restrict__ he_cur,
    int* __restrict__ n_start, int* __restrict__ n_cur) {
  int i = blockIdx.x * 256 + threadIdx.x;
  if (i < N_HE) {
    int s = atomicAdd(&totals[0], he_deg[i]);
    he_start[i] = s;
    he_cur[i] = s;
  }
  if (i < N_NODES) {
    int s = atomicAdd(&totals[1], n_deg[i]);
    n_start[i] = s;
    n_cur[i] = s;
  }
}

__global__ __launch_bounds__(256) void fill_kernel(
    const int* __restrict__ node_idx, const int* __restrict__ he_idx,
    int* __restrict__ he_cur, int* __restrict__ n_cur,
    int* __restrict__ he_list, int* __restrict__ n_list) {
  int c = blockIdx.x * 256 + threadIdx.x;
  if (c < N_CONN) {
    int n = node_idx[c];
    int e = he_idx[c];
    int p = atomicAdd(&he_cur[e], 1);
    he_list[p] = n;
    int q = atomicAdd(&n_cur[n], 1);
    n_list[q] = e;
  }
}

// ---------------------------------------------------------------------------
// Weight convert+transpose: Wt[n][k] = bf16(W[k][n]).
// ---------------------------------------------------------------------------
__global__ __launch_bounds__(256) void convert_w(
    const float* __restrict__ Wnode, const float* __restrict__ Whe,
    unsigned short* __restrict__ Wt) {
  int m = blockIdx.x >> 4;
  int tile = blockIdx.x & 15;
  int k0 = (tile >> 2) * 64, n0 = (tile & 3) * 64;
  const float* Win = (m < 2) ? (Wnode + (size_t)m * 65536)
                             : (Whe + (size_t)(m - 2) * 65536);
  unsigned short* Wout = Wt + (size_t)m * 65536;
  __shared__ unsigned short T[64][65];
  int t = threadIdx.x;
  int r = t >> 6, c = t & 63;
  #pragma unroll 4
  for (int i = 0; i < 16; ++i) {
    int kr = i * 4 + r;
    T[kr][c] = f2bf(Win[(size_t)(k0 + kr) * 256 + n0 + c]);
  }
  __syncthreads();
  #pragma unroll 4
  for (int i = 0; i < 16; ++i) {
    int nr = i * 4 + r;
    Wout[(size_t)(n0 + nr) * 256 + k0 + c] = T[c][nr];
  }
}

// ---------------------------------------------------------------------------
// GEMM: bf16 A staged via global_load_lds width=16 (A/B-validated winner).
// Double-buffered (2x32KB), grid-stride; one __syncthreads per tile.
// ---------------------------------------------------------------------------
__global__ __launch_bounds__(512, 4) void gemm_pipe(
    const unsigned short* __restrict__ A, const unsigned short* __restrict__ Wt,
    const float* __restrict__ bias, unsigned short* __restrict__ out,
    int M, int ntiles) {
  __shared__ unsigned short As[2][64 * 256];  // 2 x 32 KB
  const int t = threadIdx.x;
  const int wave = t >> 6, lane = t & 63;
  const int l31 = lane & 31, lhi = lane >> 5;
  const int colbase = wave * 32;

  // ---- preload + pin B ----
  f32x4 B[16];
  {
    const unsigned short* bp = Wt + (size_t)(colbase + l31) * 256 + lhi * 8;
    #pragma unroll
    for (int kc = 0; kc < 16; ++kc)
      B[kc] = *(const f32x4*)(bp + kc * 16);
  }
  #pragma unroll
  for (int kc = 0; kc < 16; ++kc)
    asm volatile("" : "+v"(B[kc]));
  float biasv = bias[colbase + l31];

  // Per-lane swizzled source offsets (ushort units within a 64x256 tile).
  int goff[4];
  #pragma unroll
  for (int i = 0; i < 4; ++i) {
    int c = i * 512 + t;
    int row = c >> 5, s = c & 31;
    int ss = (s & 24) | ((s & 7) ^ (row & 7));
    goff[i] = row * 256 + ss * 8;
  }

  // ---- prologue: stage first tile into buf 0 ----
  {
    const unsigned short* base = A + (size_t)blockIdx.x * 64 * 256;
    #pragma unroll
    for (int i = 0; i < 4; ++i) {
      __builtin_amdgcn_global_load_lds(
          (const __attribute__((address_space(1))) void*)(base + goff[i]),
          (__attribute__((address_space(3))) void*)((char*)As[0] + i * 8192 + wave * 1024),
          16, 0, 0);
    }
  }

  int cur = 0;
  for (int tile = blockIdx.x; tile < ntiles; tile += gridDim.x) {
    __syncthreads();  // drains vmcnt -> As[cur] DMA complete; prev compute done

    const int next = tile + gridDim.x;
    if (next < ntiles) {
      const unsigned short* base = A + (size_t)next * 64 * 256;
      #pragma unroll
      for (int i = 0; i < 4; ++i) {
        __builtin_amdgcn_global_load_lds(
            (const __attribute__((address_space(1))) void*)(base + goff[i]),
            (__attribute__((address_space(3))) void*)((char*)As[cur ^ 1] + i * 8192 + wave * 1024),
            16, 0, 0);
      }
    }

    // ---- compute current tile ----
    const int row0 = tile * 64;
    const char* Ab = (const char*)As[cur];
    f32x16 acc0 = (f32x16)0.f, acc1 = (f32x16)0.f;
    #pragma unroll
    for (int kc = 0; kc < 16; ++kc) {
      unsigned int ad0 = (unsigned)(l31 * 512 + kc * 32 + lhi * 16) ^ (unsigned)((l31 & 7) << 4);
      short8 a0 = *(const short8*)(Ab + ad0);
      unsigned int ad1 = (unsigned)((32 + l31) * 512 + kc * 32 + lhi * 16) ^ (unsigned)((l31 & 7) << 4);
      short8 a1 = *(const short8*)(Ab + ad1);
      short8 b = __builtin_bit_cast(short8, B[kc]);
      acc0 = __builtin_amdgcn_mfma_f32_32x32x16_bf16(a0, b, acc0, 0, 0, 0);
      acc1 = __builtin_amdgcn_mfma_f32_32x32x16_bf16(a1, b, acc1, 0, 0, 0);
    }

    const int col = colbase + l31;
    #pragma unroll
    for (int rt = 0; rt < 2; ++rt) {
      #pragma unroll
      for (int reg = 0; reg < 16; ++reg) {
        int row = (reg & 3) + 8 * (reg >> 2) + 4 * lhi;
        int grow = row0 + rt * 32 + row;
        if (grow < M) {
          float v = ((rt == 0) ? acc0[reg] : acc1[reg]) + biasv;
          out[(size_t)grow * D + col] = f2bf(v);
        }
      }
    }
    cur ^= 1;
  }
}

// ---------------------------------------------------------------------------
// Fused: gather nodes -> hyperedge mean (into swizzled LDS A-tile), then
// 32x32x16 MFMA with pinned-B: he_out = (mean @ We + be) * hw.  bf16 in/out.
// Gather: 2 rows per wave concurrently, 32 lanes x 16B per row (16 loads in
// flight per wave at unroll-8). Per-element accumulation order unchanged.
// ---------------------------------------------------------------------------
__global__ __launch_bounds__(512, 4) void he_fused(
    const unsigned short* __restrict__ xt, const int* __restrict__ he_start,
    const int* __restrict__ he_deg, const int* __restrict__ he_list,
    const unsigned short* __restrict__ Wt, const float* __restrict__ bias,
    const float* __restrict__ hwp, unsigned short* __restrict__ he_out) {
  __shared__ unsigned short As[64 * 256];  // 32 KB
  const int t = threadIdx.x;
  const int wave = t >> 6, lane = t & 63;
  const int l31 = lane & 31, lhi = lane >> 5;
  const int colbase = wave * 32;

  // ---- preload + pin B ----
  f32x4 B[16];
  {
    const unsigned short* bp = Wt + (size_t)(colbase + l31) * 256 + lhi * 8;
    #pragma unroll
    for (int kc = 0; kc < 16; ++kc)
      B[kc] = *(const f32x4*)(bp + kc * 16);
  }
  #pragma unroll
  for (int kc = 0; kc < 16; ++kc)
    asm volatile("" : "+v"(B[kc]));
  float biasv = bias[colbase + l31];

  // ---- gather phase: wave gathers rows wave*8 .. wave*8+7, 2 at a time ----
  const int e0 = blockIdx.x * 64;
  const int half = lhi;   // 0/1: which row of the pair this half-wave owns
  const int l16 = l31;    // 16B slot within the row (32 x 16B = 512B)
  for (int jp = 0; jp < 4; ++jp) {
    int row = wave * 8 + jp * 2 + half;
    int e = e0 + row;
    float a[8];
    #pragma unroll
    for (int k = 0; k < 8; ++k) a[k] = 0.f;
    float invv = 0.f;
    if (e < N_HE) {
      int s = he_start[e];
      int deg = he_deg[e];
      int i = 0;
      for (; i + 8 <= deg; i += 8) {
        int n0 = he_list[s + i + 0];
        int n1 = he_list[s + i + 1];
        int n2 = he_list[s + i + 2];
        int n3 = he_list[s + i + 3];
        int n4 = he_list[s + i + 4];
        int n5 = he_list[s + i + 5];
        int n6 = he_list[s + i + 6];
        int n7 = he_list[s + i + 7];
        short8 v0 = ((const short8*)(xt + (size_t)n0 * D))[l16];
        short8 v1 = ((const short8*)(xt + (size_t)n1 * D))[l16];
        short8 v2 = ((const short8*)(xt + (size_t)n2 * D))[l16];
        short8 v3 = ((const short8*)(xt + (size_t)n3 * D))[l16];
        short8 v4 = ((const short8*)(xt + (size_t)n4 * D))[l16];
        short8 v5 = ((const short8*)(xt + (size_t)n5 * D))[l16];
        short8 v6 = ((const short8*)(xt + (size_t)n6 * D))[l16];
        short8 v7 = ((const short8*)(xt + (size_t)n7 * D))[l16];
        #pragma unroll
        for (int k = 0; k < 8; ++k)
          a[k] += bf2f((unsigned short)v0[k]) + bf2f((unsigned short)v1[k])
                + bf2f((unsigned short)v2[k]) + bf2f((unsigned short)v3[k])
                + bf2f((unsigned short)v4[k]) + bf2f((unsigned short)v5[k])
                + bf2f((unsigned short)v6[k]) + bf2f((unsigned short)v7[k]);
      }
      for (; i + 4 <= deg; i += 4) {
        int n0 = he_list[s + i + 0];
        int n1 = he_list[s + i + 1];
        int n2 = he_list[s + i + 2];
        int n3 = he_list[s + i + 3];
        short8 v0 = ((const short8*)(xt + (size_t)n0 * D))[l16];
        short8 v1 = ((const short8*)(xt + (size_t)n1 * D))[l16];
        short8 v2 = ((const short8*)(xt + (size_t)n2 * D))[l16];
        short8 v3 = ((const short8*)(xt + (size_t)n3 * D))[l16];
        #pragma unroll
        for (int k = 0; k < 8; ++k)
          a[k] += bf2f((unsigned short)v0[k]) + bf2f((unsigned short)v1[k])
                + bf2f((unsigned short)v2[k]) + bf2f((unsigned short)v3[k]);
      }
      for (; i < deg; ++i) {
        int n = he_list[s + i];
        short8 v = ((const short8*)(xt + (size_t)n * D))[l16];
        #pragma unroll
        for (int k = 0; k < 8; ++k) a[k] += bf2f((unsigned short)v[k]);
      }
      invv = 1.0f / ((float)deg + MEAN_EPS);
    }
    short8 o;
    #pragma unroll
    for (int k = 0; k < 8; ++k) o[k] = (short)f2bf(a[k] * invv);
    unsigned int byte = (unsigned)(row * 512 + l16 * 16) ^ (unsigned)((row & 7) << 4);
    *(short8*)((char*)As + byte) = o;
  }
  __syncthreads();

  // ---- MFMA phase ----
  f32x16 acc0 = (f32x16)0.f, acc1 = (f32x16)0.f;
  #pragma unroll
  for (int kc = 0; kc < 16; ++kc) {
    unsigned int ad0 = (unsigned)(l31 * 512 + kc * 32 + lhi * 16) ^ (unsigned)((l31 & 7) << 4);
    short8 a0 = *(const short8*)((const char*)As + ad0);
    unsigned int ad1 = (unsigned)((32 + l31) * 512 + kc * 32 + lhi * 16) ^ (unsigned)((l31 & 7) << 4);
    short8 a1 = *(const short8*)((const char*)As + ad1);
    short8 b = __builtin_bit_cast(short8, B[kc]);
    acc0 = __builtin_amdgcn_mfma_f32_32x32x16_bf16(a0, b, acc0, 0, 0, 0);
    acc1 = __builtin_amdgcn_mfma_f32_32x32x16_bf16(a1, b, acc1, 0, 0, 0);
  }

  const int col = colbase + l31;
  #pragma unroll
  for (int rt = 0; rt < 2; ++rt) {
    #pragma unroll
    for (int reg = 0; reg < 16; ++reg) {
      int row = (reg & 3) + 8 * (reg >> 2) + 4 * lhi;
      int grow = e0 + rt * 32 + row;
      if (grow < N_HE) {
        float v = (((rt == 0) ? acc0[reg] : acc1[reg]) + biasv) * hwp[grow];
        he_out[(size_t)grow * D + col] = f2bf(v);
      }
    }
  }
}

// ---------------------------------------------------------------------------
// Fused finalize, 32-lane-per-node (2 nodes/wave, 8/block): gather he -> mean,
// + xt, LayerNorm (5-round shfl within 32-lane group), LeakyReLU, opt residual.
// xt row load hoisted above the gather so it issues with the first batch.
// ---------------------------------------------------------------------------
template <int O_F32>
__global__ __launch_bounds__(256) void finalize_k(
    const unsigned short* __restrict__ he_feat, const int* __restrict__ n_start,
    const int* __restrict__ n_deg, const int* __restrict__ n_list,
    const unsigned short* __restrict__ xt, const float* __restrict__ g,
    const float* __restrict__ b, const unsigned short* __restrict__ res,
    void* __restrict__ outv, int add_res) {
  int node = blockIdx.x * 8 + (threadIdx.x >> 5);
  if (node >= N_NODES) return;
  int lane = threadIdx.x & 31;  // 32 lanes x 16 B = 512 B row
  int s = n_start[node];
  int deg = n_deg[node];

  short8 xv = ((const short8*)(xt + (size_t)node * D))[lane];  // independent: issue early

  float a[8];
  #pragma unroll
  for (int k = 0; k < 8; ++k) a[k] = 0.f;

  int i = 0;
  for (; i + 4 <= deg; i += 4) {
    int e0 = n_list[s + i + 0];
    int e1 = n_list[s + i + 1];
    int e2 = n_list[s + i + 2];
    int e3 = n_list[s + i + 3];
    short8 v0 = ((const short8*)(he_feat + (size_t)e0 * D))[lane];
    short8 v1 = ((const short8*)(he_feat + (size_t)e1 * D))[lane];
    short8 v2 = ((const short8*)(he_feat + (size_t)e2 * D))[lane];
    short8 v3 = ((const short8*)(he_feat + (size_t)e3 * D))[lane];
    #pragma unroll
    for (int k = 0; k < 8; ++k)
      a[k] += bf2f((unsigned short)v0[k]) + bf2f((unsigned short)v1[k])
            + bf2f((unsigned short)v2[k]) + bf2f((unsigned short)v3[k]);
  }
  for (; i < deg; ++i) {
    int e = n_list[s + i];
    short8 v = ((const short8*)(he_feat + (size_t)e * D))[lane];
    #pragma unroll
    for (int k = 0; k < 8; ++k) a[k] += bf2f((unsigned short)v[k]);
  }
  float inv = deg > 0 ? 1.0f / (float)deg : 0.0f;

  float h[8];
  #pragma unroll
  for (int k = 0; k < 8; ++k) h[k] = a[k] * inv + bf2f((unsigned short)xv[k]);

  float sum = 0.f, ss = 0.f;
  #pragma unroll
  for (int k = 0; k < 8; ++k) { sum += h[k]; ss += h[k] * h[k]; }
  #pragma unroll
  for (int o = 16; o > 0; o >>= 1) {  // masks <32: stays within the group
    sum += __shfl_xor(sum, o);
    ss  += __shfl_xor(ss, o);
  }
  float mu  = sum * (1.0f / D);
  float var = ss * (1.0f / D) - mu * mu;
  float rstd = rsqrtf(var + LN_EPS);

  float4 gv0 = ((const float4*)g)[lane * 2];
  float4 gv1 = ((const float4*)g)[lane * 2 + 1];
  float4 bv0 = ((const float4*)b)[lane * 2];
  float4 bv1 = ((const float4*)b)[lane * 2 + 1];
  float gg[8] = {gv0.x, gv0.y, gv0.z, gv0.w, gv1.x, gv1.y, gv1.z, gv1.w};
  float bb[8] = {bv0.x, bv0.y, bv0.z, bv0.w, bv1.x, bv1.y, bv1.z, bv1.w};

  float o8[8];
  #pragma unroll
  for (int k = 0; k < 8; ++k) {
    float v = (h[k] - mu) * rstd * gg[k] + bb[k];
    o8[k] = v >= 0.f ? v : v * SLOPE;
  }

  if (add_res) {
    short8 rv = ((const short8*)(res + (size_t)node * D))[lane];
    #pragma unroll
    for (int k = 0; k < 8; ++k) o8[k] += bf2f((unsigned short)rv[k]);
  }

  if (O_F32) {
    float* out = (float*)outv + (size_t)node * D;
    ((float4*)out)[lane * 2]     = make_float4(o8[0], o8[1], o8[2], o8[3]);
    ((float4*)out)[lane * 2 + 1] = make_float4(o8[4], o8[5], o8[6], o8[7]);
  } else {
    short8 ov;
    #pragma unroll
    for (int k = 0; k < 8; ++k) ov[k] = (short)f2bf(o8[k]);
    ((short8*)((unsigned short*)outv + (size_t)node * D))[lane] = ov;
  }
}

// ---------------------------------------------------------------------------
extern "C" void kernel_launch(void* const* d_in, const int* in_sizes, int n_in,
                              void* d_out, int out_size, void* d_ws, size_t ws_size,
                              hipStream_t stream) {
  const float* x       = (const float*)d_in[0];
  const float* node_W  = (const float*)d_in[1];  // [2,256,256]
  const float* node_b  = (const float*)d_in[2];  // [2,256]
  const float* he_W    = (const float*)d_in[3];
  const float* he_b    = (const float*)d_in[4];
  const float* ln_g    = (const float*)d_in[5];
  const float* ln_b    = (const float*)d_in[6];
  const float* hw      = (const float*)d_in[7];  // [25000]
  const int*   node_idx = (const int*)d_in[8];
  const int*   he_idx   = (const int*)d_in[9];

  // Workspace layout (bf16 intermediates; GEMM inputs padded to N_PAD rows).
  unsigned short* x_bf   = (unsigned short*)d_ws;           // N_PAD*256
  unsigned short* out_bf = x_bf + (size_t)N_PAD * D;        // N_PAD*256
  unsigned short* xt     = out_bf + (size_t)N_PAD * D;      // 100000*256
  unsigned short* he_buf = xt + (size_t)N_NODES * D;        // 25000*256
  unsigned short* Wt_all = he_buf + (size_t)N_HE * D;       // 4*65536
  int* he_deg   = (int*)(Wt_all + 4 * 65536);               // 25000
  int* n_deg    = he_deg + N_HE;                            // 100000
  int* totals   = n_deg + N_NODES;                          // 2
  int* he_start = totals + 2;                               // 25000
  int* he_cur   = he_start + N_HE;                          // 25000
  int* n_start  = he_cur + N_HE;                            // 100000
  int* n_cur    = n_start + N_NODES;                        // 100000
  int* he_list  = n_cur + N_NODES;                          // 400000
  int* n_list   = he_list + N_CONN;                         // 400000

  // --- x -> bf16 ---
  conv_x<<<2048, 256, 0, stream>>>(x, x_bf, N_NODES * D / 8);

  // --- Weight convert+transpose (all 4 matrices, one dispatch) ---
  convert_w<<<64, 256, 0, stream>>>(node_W, he_W, Wt_all);

  // --- Build adjacency (every call; indices are constant inputs) ---
  hipMemsetAsync(he_deg, 0, (size_t)(N_HE + N_NODES + 2) * sizeof(int), stream);
  hist_kernel<<<(N_CONN + 255) / 256, 256, 0, stream>>>(node_idx, he_idx, he_deg, n_deg);
  alloc_kernel<<<(N_NODES + 255) / 256, 256, 0, stream>>>(
      he_deg, n_deg, totals, he_start, he_cur, n_start, n_cur);
  fill_kernel<<<(N_CONN + 255) / 256, 256, 0, stream>>>(
      node_idx, he_idx, he_cur, n_cur, he_list, n_list);

  const int ntiles_node = N_PAD / 64;        // 1563
  const int nblk_he     = (N_HE + 63) / 64;  // 391

  for (int l = 0; l < 2; ++l) {
    const unsigned short* Wtn = Wt_all + (size_t)l * 65536;
    const unsigned short* Wte = Wt_all + (size_t)(2 + l) * 65536;
    const float* bn = node_b + (size_t)l * D;
    const float* be = he_b + (size_t)l * D;
    const float* g  = ln_g + (size_t)l * D;
    const float* bb = ln_b + (size_t)l * D;

    gemm_pipe<<<512, 512, 0, stream>>>(
        (l == 0) ? x_bf : out_bf, Wtn, bn, xt, N_NODES, ntiles_node);
    he_fused<<<nblk_he, 512, 0, stream>>>(
        xt, he_start, he_deg, he_list, Wte, be, hw, he_buf);
    if (l == 0) {
      finalize_k<0><<<(N_NODES + 7) / 8, 256, 0, stream>>>(
          he_buf, n_start, n_deg, n_list, xt, g, bb, nullptr, out_bf, 0);
    } else {
      finalize_k<1><<<(N_NODES + 7) / 8, 256, 0, stream>>>(
          he_buf, n_start, n_deg, n_list, xt, g, bb, out_bf, d_out, 1);
    }
  }
}